// Round 5
// baseline (282.254 us; speedup 1.0000x reference)
//
#include <hip/hip_runtime.h>
#include <math.h>

#define N 8192
#define C 10
#define NUM_ITERS 5
#define CBLOCK 256        /* combine block size */
#define FBLOCK 512        /* filter block: 8 waves */
#define JCH 16
#define JT (N / JCH)      /* 512 j's staged per block */
#define IBLK 256          /* i's per filter block: 8 waves x 32 */
#define NIB (N / IBLK)    /* 32 */
#define LOG2E 1.44269504088896340736f
#define C3 (LOG2E / 64.0f)
#define PROW (JT + 8)     /* padded LDS row for p (f16 elems) */

typedef _Float16 half8 __attribute__((ext_vector_type(8)));
typedef _Float16 half4 __attribute__((ext_vector_type(4)));
typedef float f32x4 __attribute__((ext_vector_type(4)));

// ws byte offsets:
//   ajs half8[N] : j-side spatial aug features   [f*C3 x3, 0, 0,0,-h3*C3, 1]
//   ajb half8[N] : j-side bilateral aug features [f*L2E x6, -h6*L2E, 1]
//   pf  f16[16][N] : softmax probs, rows 10..15 zero
//   acc float[20][N] : rows 0-9 spatial_out, 10-19 bilateral_out (atomic)
#define WS_AJS 0
#define WS_AJB (N * 16)
#define WS_PF  (N * 32)
#define WS_ACC (N * 64)

// do_filter=0: q=unaries, zero acc, ALSO build ajs/ajb (prep fused).
// is_last=1: write q to out (skip softmax).
__global__ __launch_bounds__(CBLOCK) void combine_kernel(
    const float* __restrict__ unaries, const float* __restrict__ feat,
    const float* __restrict__ SW, const float* __restrict__ BW,
    const float* __restrict__ CM, float* __restrict__ acc,
    _Float16* __restrict__ pf, half8* __restrict__ ajs, half8* __restrict__ ajb,
    float* __restrict__ out, int do_filter, int is_last) {
    __shared__ float sSW[100], sBW[100], sCM[100];
    int t = threadIdx.x;
    if (t < 100) { sSW[t] = SW[t]; sBW[t] = BW[t]; sCM[t] = CM[t]; }
    __syncthreads();
    int n = blockIdx.x * CBLOCK + t;

    float q[C];
    if (do_filter) {
        float sp[C], bl[C];
#pragma unroll
        for (int k = 0; k < C; ++k) {
            sp[k] = acc[k * N + n];        acc[k * N + n] = 0.0f;
            bl[k] = acc[(C + k) * N + n];  acc[(C + k) * N + n] = 0.0f;
        }
        float msg[C];
#pragma unroll
        for (int c = 0; c < C; ++c) {
            float m = 0.0f;
#pragma unroll
            for (int k = 0; k < C; ++k)
                m += sSW[c * C + k] * sp[k] + sBW[c * C + k] * bl[k];
            msg[c] = m;
        }
#pragma unroll
        for (int c = 0; c < C; ++c) {
            float pw = 0.0f;
#pragma unroll
            for (int k = 0; k < C; ++k) pw += sCM[c * C + k] * msg[k];
            q[c] = unaries[c * N + n] - pw;
        }
    } else {
#pragma unroll
        for (int c = 0; c < C; ++c) q[c] = unaries[c * N + n];
#pragma unroll
        for (int k = 0; k < 2 * C; ++k) acc[k * N + n] = 0.0f;
        // prep: augmented j-side feature vectors
        float f[6];
#pragma unroll
        for (int d = 0; d < 6; ++d) f[d] = feat[d * N + n];
        float h3 = 0.5f * (f[0] * f[0] + f[1] * f[1] + f[2] * f[2]);
        float h6 = h3 + 0.5f * (f[3] * f[3] + f[4] * f[4] + f[5] * f[5]);
        half8 a = {};
        a[0] = (_Float16)(f[0] * C3);
        a[1] = (_Float16)(f[1] * C3);
        a[2] = (_Float16)(f[2] * C3);
        a[6] = (_Float16)(-h3 * C3);
        a[7] = (_Float16)1.0f;
        ajs[n] = a;
        half8 b;
#pragma unroll
        for (int d = 0; d < 6; ++d) b[d] = (_Float16)(f[d] * LOG2E);
        b[6] = (_Float16)(-h6 * LOG2E);
        b[7] = (_Float16)1.0f;
        ajb[n] = b;
    }

    if (is_last) {
#pragma unroll
        for (int c = 0; c < C; ++c) out[c * N + n] = q[c];
    } else {
        float m = q[0];
#pragma unroll
        for (int c = 1; c < C; ++c) m = fmaxf(m, q[c]);
        float e[C], s = 0.0f;
#pragma unroll
        for (int c = 0; c < C; ++c) {
            e[c] = __builtin_amdgcn_exp2f((q[c] - m) * LOG2E);
            s += e[c];
        }
        float inv = 1.0f / s;
#pragma unroll
        for (int c = 0; c < C; ++c) pf[c * N + n] = (_Float16)(e[c] * inv);
#pragma unroll
        for (int c = C; c < 16; ++c) pf[c * N + n] = (_Float16)0.0f;
    }
}

static __device__ inline half4 expcvt(f32x4 d) {
    half4 r;
    r[0] = (_Float16)__builtin_amdgcn_exp2f(d[0]);
    r[1] = (_Float16)__builtin_amdgcn_exp2f(d[1]);
    r[2] = (_Float16)__builtin_amdgcn_exp2f(d[2]);
    r[3] = (_Float16)__builtin_amdgcn_exp2f(d[3]);
    return r;
}

__global__ __launch_bounds__(FBLOCK, 4) void filter_kernel(
    const float* __restrict__ feat, const half4* __restrict__ ajs,
    const half4* __restrict__ ajb, const _Float16* __restrict__ pf,
    float* __restrict__ acc) {
    __shared__ half4 ajs_l[JT * 2];        //  8 KB  [j][h]
    __shared__ half4 ajb_l[JT * 2];        //  8 KB
    __shared__ _Float16 p_l[16 * PROW];    // 16.25 KB

    int t = threadIdx.x;
    int ibb = blockIdx.x * IBLK;
    int jbase = blockIdx.y * JT;

    // ---- stage j-chunk (coalesced float4) ----
    {
        const float4* s0 = (const float4*)(ajs + (size_t)jbase * 2);
        const float4* s1 = (const float4*)(ajb + (size_t)jbase * 2);
        float4* d0 = (float4*)ajs_l;
        float4* d1 = (float4*)ajb_l;
        for (int k = t; k < JT; k += FBLOCK) { d0[k] = s0[k]; d1[k] = s1[k]; }
        const float4* ps = (const float4*)pf;
        float4* pd = (float4*)p_l;
        for (int k = t; k < 16 * (JT / 8); k += FBLOCK) {
            int c = k >> 6, off = k & 63;
            pd[c * (PROW / 8) + off] = ps[c * (N / 8) + (jbase >> 3) + off];
        }
    }
    __syncthreads();

    int lane = t & 63;
    int w = t >> 6;
    int il = lane & 15;
    int quad = lane >> 4;
    int h = quad & 1;
    bool klo = (quad < 2);
    int i0 = ibb + w * 32;   // wave's 32 i's: subtile0 = i0.., subtile1 = i0+16..

    const half4 hz = {};

    // B1 fragments (i-side aug), K=16 layout: lane holds B[k=quad*4+r][n=il]
    half4 b1s0, b1s1, b1b0, b1b1;
#pragma unroll
    for (int s = 0; s < 2; ++s) {
        int i = i0 + s * 16 + il;
        float g0 = feat[0 * N + i], g1 = feat[1 * N + i], g2 = feat[2 * N + i];
        float g3 = feat[3 * N + i], g4 = feat[4 * N + i], g5 = feat[5 * N + i];
        float h3 = 0.5f * (g0 * g0 + g1 * g1 + g2 * g2);
        float h6 = h3 + 0.5f * (g3 * g3 + g4 * g4 + g5 * g5);
        half4 slo = {(_Float16)g0, (_Float16)g1, (_Float16)g2, (_Float16)0.0f};
        half4 shi = {(_Float16)0.0f, (_Float16)0.0f, (_Float16)1.0f, (_Float16)(-h3 * C3)};
        half4 blo = {(_Float16)g0, (_Float16)g1, (_Float16)g2, (_Float16)g3};
        half4 bhi = {(_Float16)g4, (_Float16)g5, (_Float16)1.0f, (_Float16)(-h6 * LOG2E)};
        half4 vs = klo ? (h ? shi : slo) : hz;
        half4 vb = klo ? (h ? bhi : blo) : hz;
        if (s == 0) { b1s0 = vs; b1b0 = vb; } else { b1s1 = vs; b1b1 = vb; }
    }

    f32x4 as0 = {0.f, 0.f, 0.f, 0.f}, as1 = {0.f, 0.f, 0.f, 0.f};
    f32x4 ab0 = {0.f, 0.f, 0.f, 0.f}, ab1 = {0.f, 0.f, 0.f, 0.f};
    const f32x4 zero = {0.f, 0.f, 0.f, 0.f};

#pragma unroll 2
    for (int jb = 0; jb < JT; jb += 32) {
        int j0 = jb, j1 = jb + 16;
        // hoisted LDS reads (both groups) so latency overlaps
        half4 vs0 = ajs_l[(j0 + il) * 2 + h];
        half4 vb0 = ajb_l[(j0 + il) * 2 + h];
        half4 vs1 = ajs_l[(j1 + il) * 2 + h];
        half4 vb1 = ajb_l[(j1 + il) * 2 + h];
        half4 p2_0 = *(const half4*)&p_l[il * PROW + j0 + quad * 4];
        half4 p2_1 = *(const half4*)&p_l[il * PROW + j1 + quad * 4];
        half4 a1s_0 = klo ? vs0 : hz;
        half4 a1b_0 = klo ? vb0 : hz;
        half4 a1s_1 = klo ? vs1 : hz;
        half4 a1b_1 = klo ? vb1 : hz;

        // GEMM-1: S^T[j][i] in C/D layout (8 independent chains)
        f32x4 d0 = __builtin_amdgcn_mfma_f32_16x16x16f16(a1s_0, b1s0, zero, 0, 0, 0);
        f32x4 d1 = __builtin_amdgcn_mfma_f32_16x16x16f16(a1s_0, b1s1, zero, 0, 0, 0);
        f32x4 d2 = __builtin_amdgcn_mfma_f32_16x16x16f16(a1b_0, b1b0, zero, 0, 0, 0);
        f32x4 d3 = __builtin_amdgcn_mfma_f32_16x16x16f16(a1b_0, b1b1, zero, 0, 0, 0);
        f32x4 d4 = __builtin_amdgcn_mfma_f32_16x16x16f16(a1s_1, b1s0, zero, 0, 0, 0);
        f32x4 d5 = __builtin_amdgcn_mfma_f32_16x16x16f16(a1s_1, b1s1, zero, 0, 0, 0);
        f32x4 d6 = __builtin_amdgcn_mfma_f32_16x16x16f16(a1b_1, b1b0, zero, 0, 0, 0);
        f32x4 d7 = __builtin_amdgcn_mfma_f32_16x16x16f16(a1b_1, b1b1, zero, 0, 0, 0);

        // exp2 + cvt: C/D layout == A-operand layout of 16x16x16f16 (k=quad*4+r)
        half4 w0 = expcvt(d0), w1 = expcvt(d1), w2 = expcvt(d2), w3 = expcvt(d3);
        half4 w4 = expcvt(d4), w5 = expcvt(d5), w6 = expcvt(d6), w7 = expcvt(d7);

        // GEMM-2: out[i][c] += w[i][j] * p[c][j]
        as0 = __builtin_amdgcn_mfma_f32_16x16x16f16(w0, p2_0, as0, 0, 0, 0);
        as1 = __builtin_amdgcn_mfma_f32_16x16x16f16(w1, p2_0, as1, 0, 0, 0);
        ab0 = __builtin_amdgcn_mfma_f32_16x16x16f16(w2, p2_0, ab0, 0, 0, 0);
        ab1 = __builtin_amdgcn_mfma_f32_16x16x16f16(w3, p2_0, ab1, 0, 0, 0);
        as0 = __builtin_amdgcn_mfma_f32_16x16x16f16(w4, p2_1, as0, 0, 0, 0);
        as1 = __builtin_amdgcn_mfma_f32_16x16x16f16(w5, p2_1, as1, 0, 0, 0);
        ab0 = __builtin_amdgcn_mfma_f32_16x16x16f16(w6, p2_1, ab0, 0, 0, 0);
        ab1 = __builtin_amdgcn_mfma_f32_16x16x16f16(w7, p2_1, ab1, 0, 0, 0);
    }

    // writeout: lane holds D2[i_off = quad*4+r][c = il] per subtile/filter
    if (il < C) {
#pragma unroll
        for (int r = 0; r < 4; ++r) {
            int ia = i0 + quad * 4 + r;
            int ib2 = ia + 16;
            atomicAdd(&acc[il * N + ia], as0[r]);
            atomicAdd(&acc[il * N + ib2], as1[r]);
            atomicAdd(&acc[(C + il) * N + ia], ab0[r]);
            atomicAdd(&acc[(C + il) * N + ib2], ab1[r]);
        }
    }
}

extern "C" void kernel_launch(void* const* d_in, const int* in_sizes, int n_in,
                              void* d_out, int out_size, void* d_ws, size_t ws_size,
                              hipStream_t stream) {
    const float* unaries = (const float*)d_in[0];   // [10, 8192]
    const float* feat    = (const float*)d_in[1];   // [6, 8192]
    const float* SW      = (const float*)d_in[2];   // [10,10]
    const float* BW      = (const float*)d_in[3];   // [10,10]
    const float* CM      = (const float*)d_in[4];   // [10,10]
    float* out = (float*)d_out;

    char* ws = (char*)d_ws;
    half8* ajs    = (half8*)(ws + WS_AJS);
    half8* ajb    = (half8*)(ws + WS_AJB);
    _Float16* pf  = (_Float16*)(ws + WS_PF);
    float* acc    = (float*)(ws + WS_ACC);

    combine_kernel<<<N / CBLOCK, CBLOCK, 0, stream>>>(unaries, feat, SW, BW, CM, acc,
                                                      pf, ajs, ajb, out, 0, 0);
    for (int it = 1; it <= NUM_ITERS; ++it) {
        filter_kernel<<<dim3(NIB, JCH), FBLOCK, 0, stream>>>(feat, (const half4*)ajs,
                                                             (const half4*)ajb, pf, acc);
        combine_kernel<<<N / CBLOCK, CBLOCK, 0, stream>>>(unaries, feat, SW, BW, CM, acc,
                                                          pf, ajs, ajb, out,
                                                          1, it == NUM_ITERS ? 1 : 0);
    }
}